// Round 3
// baseline (877.723 us; speedup 1.0000x reference)
//
#include <hip/hip_runtime.h>
#include <hip/hip_bf16.h>

typedef __hip_bfloat16 bf16;

#define DEV static __device__ __forceinline__

DEV float blo(unsigned w){ return __uint_as_float(w << 16); }
DEV float bhi(unsigned w){ return __uint_as_float(w & 0xffff0000u); }
DEV unsigned short f2bu(float x){ bf16 h = __float2bfloat16(x); unsigned short u; __builtin_memcpy(&u, &h, 2); return u; }
DEV unsigned pack2(float a, float b){ return (unsigned)f2bu(a) | ((unsigned)f2bu(b) << 16); }

// Problem dims: B=8, K=512, C=256, HEADS=8, D=32, N=64, FF=1024, HT=9
// rows r = b*512 + k, RTOT = 4096
// Inputs: float32. Output: float32. Workspace intermediates qk/fctx/h1: bf16.

// ---------------------------------------------------------------- K1: q = query @ Wq + bq
__global__ __launch_bounds__(256) void k_qproj(const float* __restrict__ query,
    const float* __restrict__ Wq, const float* __restrict__ bq, float* __restrict__ q)
{
  __shared__ float ins[16][256];
  const int t = threadIdx.x;
  const int r0 = blockIdx.x * 16;
  {
    int row = t >> 4, c0 = (t & 15) * 16;
    const float4* src = (const float4*)(query + (size_t)(r0 + row) * 256 + c0);
    float4* d = (float4*)&ins[row][c0];
    d[0] = src[0]; d[1] = src[1]; d[2] = src[2]; d[3] = src[3];
  }
  __syncthreads();
  const int half = t >> 7, jj = t & 127;
  const int j0 = jj, j1 = jj + 128;
  float acc0[8] = {0,0,0,0,0,0,0,0}, acc1[8] = {0,0,0,0,0,0,0,0};
  for (int i = 0; i < 256; i += 4){
    float w0[4], w1[4];
    #pragma unroll
    for (int u = 0; u < 4; u++){
      w0[u] = Wq[(size_t)(i+u)*256 + j0];
      w1[u] = Wq[(size_t)(i+u)*256 + j1];
    }
    #pragma unroll
    for (int rr = 0; rr < 8; rr++){
      float4 v = *(const float4*)&ins[half*8 + rr][i];
      acc0[rr] += v.x*w0[0] + v.y*w0[1] + v.z*w0[2] + v.w*w0[3];
      acc1[rr] += v.x*w1[0] + v.y*w1[1] + v.z*w1[2] + v.w*w1[3];
    }
  }
  float bb0 = bq[j0], bb1 = bq[j1];
  #pragma unroll
  for (int rr = 0; rr < 8; rr++){
    q[(size_t)(r0 + half*8 + rr)*256 + j0] = acc0[rr] + bb0;
    q[(size_t)(r0 + half*8 + rr)*256 + j1] = acc1[rr] + bb1;
  }
}

// ------------------------------- K2: qk[r,h,c] = sum_d q[r,h*32+d]*Wk[c,h*32+d]; sbias[r,h] = q_h . bk_h
__global__ __launch_bounds__(256) void k_qk(const float* __restrict__ q,
    const float* __restrict__ Wk, const float* __restrict__ bk,
    bf16* __restrict__ qk, float* __restrict__ sbias)
{
  __shared__ float qs[16][32];
  __shared__ float wkT[32][256];
  const int t = threadIdx.x;
  const int r0 = blockIdx.x * 16;
  const int h = blockIdx.y;
  {
    int row = t >> 4, d0 = (t & 15) * 2;
    float2 v = *(const float2*)&q[(size_t)(r0 + row)*256 + h*32 + d0];
    qs[row][d0] = v.x; qs[row][d0 + 1] = v.y;
  }
  {
    #pragma unroll
    for (int g = 0; g < 8; g++){
      float4 v = *(const float4*)&Wk[(size_t)t*256 + h*32 + g*4];
      wkT[g*4+0][t] = v.x; wkT[g*4+1][t] = v.y;
      wkT[g*4+2][t] = v.z; wkT[g*4+3][t] = v.w;
    }
  }
  __syncthreads();
  float acc[16];
  #pragma unroll
  for (int j = 0; j < 16; j++) acc[j] = 0.f;
  for (int d = 0; d < 32; d += 4){
    float w[4];
    #pragma unroll
    for (int u = 0; u < 4; u++) w[u] = wkT[d+u][t];
    #pragma unroll
    for (int j = 0; j < 16; j++){
      float4 v = *(const float4*)&qs[j][d];
      acc[j] += v.x*w[0] + v.y*w[1] + v.z*w[2] + v.w*w[3];
    }
  }
  #pragma unroll
  for (int j = 0; j < 16; j++)
    qk[(size_t)(r0 + j)*2048 + h*256 + t] = __float2bfloat16(acc[j]);
  if (t < 16){
    float s = 0.f;
    for (int d = 0; d < 32; d++) s += qs[t][d] * bk[h*32 + d];
    sbias[(size_t)(r0 + t)*8 + h] = s;
  }
}

// ------------------------------- K3: main attention per (b,k): scores, bias(grid-sample), softmax, fctx
// LDS: fs 33792 + qks 8192 + sc 2048 + attn_t 2048 + tab 2592 + bw4 1024 + bix 1024 + sb 32 = 50752 B
__global__ __launch_bounds__(256) void k_attn(
    const float* __restrict__ local_feat, const float* __restrict__ local_spat,
    const float* __restrict__ rel_table, const bf16* __restrict__ qk,
    const float* __restrict__ sbias, bf16* __restrict__ fctx)
{
  __shared__ ushort fs[256][66];       // feats[c][n] in bf16, stride 66
  __shared__ float qks[8][256];
  __shared__ float sc[8][64];
  __shared__ float attn_t[64][8];
  __shared__ float tab[648];
  __shared__ float bw4[64][4];
  __shared__ int   bix[64][4];
  __shared__ float sb[8];

  const int t = threadIdx.x;
  const int r = blockIdx.x;
  const int b = r >> 9, k = r & 511;

  // stage feats: local_feat[b, c, k, n] (f32 -> bf16 in LDS)
  {
    int cb = t >> 2;             // 0..63
    int nq = (t & 3) * 16;       // 0,16,32,48
    #pragma unroll
    for (int p = 0; p < 4; p++){
      int c = p * 64 + cb;
      const float4* src = (const float4*)(local_feat + ((size_t)((b*256 + c)*512 + k))*64 + nq);
      unsigned* d = (unsigned*)&fs[c][nq];
      #pragma unroll
      for (int g = 0; g < 4; g++){
        float4 v = src[g];
        d[g*2+0] = pack2(v.x, v.y);
        d[g*2+1] = pack2(v.z, v.w);
      }
    }
  }
  // stage qk row (bf16 ws -> f32 LDS)
  {
    const uint4* src = (const uint4*)(qk + (size_t)r * 2048 + t * 8);
    uint4 a = *src;
    int h = t >> 5, c0 = (t & 31) * 8;
    float* d = &qks[h][c0];
    d[0]=blo(a.x); d[1]=bhi(a.x); d[2]=blo(a.y); d[3]=bhi(a.y);
    d[4]=blo(a.z); d[5]=bhi(a.z); d[6]=blo(a.w); d[7]=bhi(a.w);
  }
  for (int i = t; i < 648; i += 256) tab[i] = rel_table[i];
  if (t < 8) sb[t] = sbias[(size_t)r*8 + t];
  if (t < 64){
    int n = t;
    float2 sxy = *(const float2*)&local_spat[((size_t)r*64 + n)*2];
    float gx = (sxy.x + 1.0f) * 4.0f, gy = (sxy.y + 1.0f) * 4.0f;
    float x0f = floorf(gx), y0f = floorf(gy);
    int xi0 = (int)x0f, yi0 = (int)y0f;
    float wx1 = gx - x0f, wx0 = 1.0f - wx1;
    float wy1 = gy - y0f, wy0 = 1.0f - wy1;
    int xs[4] = {xi0, xi0 + 1, xi0, xi0 + 1};
    int ys[4] = {yi0, yi0, yi0 + 1, yi0 + 1};
    float ww[4] = {wy0*wx0, wy0*wx1, wy1*wx0, wy1*wx1};
    #pragma unroll
    for (int j2 = 0; j2 < 4; j2++){
      int xx = xs[j2], yy = ys[j2];
      bool valid = (xx >= 0) && (xx <= 8) && (yy >= 0) && (yy <= 8);
      int xc = min(max(xx, 0), 8), yc = min(max(yy, 0), 8);
      bix[n][j2] = yc * 9 + xc;
      bw4[n][j2] = valid ? ww[j2] : 0.0f;
    }
  }
  __syncthreads();

  // scores[h][n] = (qk_h . feats[:, n] + sbias) * scale + grid_bias
  {
    int h = t >> 5, n0 = (t & 31) * 2;
    float s0 = 0.f, s1 = 0.f;
    for (int c = 0; c < 256; c += 4){
      float4 qv = *(const float4*)&qks[h][c];
      unsigned w0 = *(const unsigned*)&fs[c+0][n0];
      unsigned w1 = *(const unsigned*)&fs[c+1][n0];
      unsigned w2 = *(const unsigned*)&fs[c+2][n0];
      unsigned w3 = *(const unsigned*)&fs[c+3][n0];
      s0 += qv.x*blo(w0) + qv.y*blo(w1) + qv.z*blo(w2) + qv.w*blo(w3);
      s1 += qv.x*bhi(w0) + qv.y*bhi(w1) + qv.z*bhi(w2) + qv.w*bhi(w3);
    }
    const float scale = 0.17677669529663687f;  // 1/sqrt(32)
    float bias0 = tab[h*81 + bix[n0][0]] * bw4[n0][0] + tab[h*81 + bix[n0][1]] * bw4[n0][1]
                + tab[h*81 + bix[n0][2]] * bw4[n0][2] + tab[h*81 + bix[n0][3]] * bw4[n0][3];
    int n1 = n0 + 1;
    float bias1 = tab[h*81 + bix[n1][0]] * bw4[n1][0] + tab[h*81 + bix[n1][1]] * bw4[n1][1]
                + tab[h*81 + bix[n1][2]] * bw4[n1][2] + tab[h*81 + bix[n1][3]] * bw4[n1][3];
    sc[h][n0] = (s0 + sb[h]) * scale + bias0;
    sc[h][n1] = (s1 + sb[h]) * scale + bias1;
  }
  __syncthreads();

  // softmax over n per head; write transposed attn
  if (t < 8){
    int h = t;
    float m = -1e30f;
    for (int n = 0; n < 64; n++) m = fmaxf(m, sc[h][n]);
    float s = 0.f;
    for (int n = 0; n < 64; n++){ float e = __expf(sc[h][n] - m); sc[h][n] = e; s += e; }
    float inv = 1.0f / s;
    for (int n = 0; n < 64; n++) attn_t[n][h] = sc[h][n] * inv;
  }
  __syncthreads();

  // fctx[h][c] = sum_n attn[h][n] * feats[c][n]; thread t owns channel c=t, all 8 heads
  {
    const int c = t;
    float f[8] = {0,0,0,0,0,0,0,0};
    for (int n = 0; n < 64; n += 2){
      unsigned wa = *(const unsigned*)&fs[c][n];
      float a0 = blo(wa), a1 = bhi(wa);
      float4 A0 = *(const float4*)&attn_t[n][0];
      float4 A1 = *(const float4*)&attn_t[n][4];
      float4 B0 = *(const float4*)&attn_t[n+1][0];
      float4 B1 = *(const float4*)&attn_t[n+1][4];
      f[0] += A0.x*a0 + B0.x*a1;  f[1] += A0.y*a0 + B0.y*a1;
      f[2] += A0.z*a0 + B0.z*a1;  f[3] += A0.w*a0 + B0.w*a1;
      f[4] += A1.x*a0 + B1.x*a1;  f[5] += A1.y*a0 + B1.y*a1;
      f[6] += A1.z*a0 + B1.z*a1;  f[7] += A1.w*a0 + B1.w*a1;
    }
    #pragma unroll
    for (int h = 0; h < 8; h++)
      fctx[(size_t)r*2048 + h*256 + c] = __float2bfloat16(f[h]);
  }
}

// ------------------------------- K4: ctx[r, h*32+d] = sum_c fctx[r,h,c]*Wv[c,h*32+d] + bv
__global__ __launch_bounds__(256) void k_ctx(const bf16* __restrict__ fctx,
    const float* __restrict__ Wv, const float* __restrict__ bv, float* __restrict__ ctx)
{
  __shared__ float fc[16][8][36];
  const int t = threadIdx.x;
  const int r0 = blockIdx.x * 16;
  const int rh = t >> 7;
  const int h  = (t >> 4) & 7;
  const int dd = t & 15;
  const int j0 = h*32 + dd*2, j1 = j0 + 1;
  float acc0[8] = {0,0,0,0,0,0,0,0}, acc1[8] = {0,0,0,0,0,0,0,0};
  for (int cb = 0; cb < 8; cb++){
    __syncthreads();
    {
      int j = t >> 4, hh = (t >> 1) & 7, cc0 = (t & 1) * 16;
      const uint4* src = (const uint4*)(fctx + (size_t)(r0 + j)*2048 + hh*256 + cb*32 + cc0);
      uint4 a = src[0], b = src[1];
      float* d = &fc[j][hh][cc0];
      d[0]=blo(a.x); d[1]=bhi(a.x); d[2]=blo(a.y); d[3]=bhi(a.y);
      d[4]=blo(a.z); d[5]=bhi(a.z); d[6]=blo(a.w); d[7]=bhi(a.w);
      d[8]=blo(b.x); d[9]=bhi(b.x); d[10]=blo(b.y); d[11]=bhi(b.y);
      d[12]=blo(b.z); d[13]=bhi(b.z); d[14]=blo(b.w); d[15]=bhi(b.w);
    }
    __syncthreads();
    for (int cc = 0; cc < 32; cc += 4){
      float2 wv[4];
      #pragma unroll
      for (int u = 0; u < 4; u++)
        wv[u] = *(const float2*)&Wv[(size_t)(cb*32 + cc + u)*256 + j0];
      #pragma unroll
      for (int rr = 0; rr < 8; rr++){
        float4 f = *(const float4*)&fc[rh*8 + rr][h][cc];
        acc0[rr] += f.x*wv[0].x + f.y*wv[1].x + f.z*wv[2].x + f.w*wv[3].x;
        acc1[rr] += f.x*wv[0].y + f.y*wv[1].y + f.z*wv[2].y + f.w*wv[3].y;
      }
    }
  }
  float bv0 = bv[j0], bv1 = bv[j1];
  #pragma unroll
  for (int rr = 0; rr < 8; rr++){
    float2 o; o.x = acc0[rr] + bv0; o.y = acc1[rr] + bv1;
    *(float2*)&ctx[(size_t)(r0 + rh*8 + rr)*256 + j0] = o;
  }
}

// ------------------------------- K5: ao = query + ctx @ Wo + bo
__global__ __launch_bounds__(256) void k_attnout(const float* __restrict__ ctx,
    const float* __restrict__ Wo, const float* __restrict__ bo,
    const float* __restrict__ query, float* __restrict__ ao)
{
  __shared__ float ins[16][256];
  const int t = threadIdx.x;
  const int r0 = blockIdx.x * 16;
  {
    int row = t >> 4, c0 = (t & 15) * 16;
    const float4* src = (const float4*)(ctx + (size_t)(r0 + row)*256 + c0);
    float4* d = (float4*)&ins[row][c0];
    d[0] = src[0]; d[1] = src[1]; d[2] = src[2]; d[3] = src[3];
  }
  __syncthreads();
  const int half = t >> 7, jj = t & 127;
  const int j0 = jj, j1 = jj + 128;
  float acc0[8] = {0,0,0,0,0,0,0,0}, acc1[8] = {0,0,0,0,0,0,0,0};
  for (int i = 0; i < 256; i += 4){
    float w0[4], w1[4];
    #pragma unroll
    for (int u = 0; u < 4; u++){
      w0[u] = Wo[(size_t)(i+u)*256 + j0];
      w1[u] = Wo[(size_t)(i+u)*256 + j1];
    }
    #pragma unroll
    for (int rr = 0; rr < 8; rr++){
      float4 v = *(const float4*)&ins[half*8 + rr][i];
      acc0[rr] += v.x*w0[0] + v.y*w0[1] + v.z*w0[2] + v.w*w0[3];
      acc1[rr] += v.x*w1[0] + v.y*w1[1] + v.z*w1[2] + v.w*w1[3];
    }
  }
  float bb0 = bo[j0], bb1 = bo[j1];
  #pragma unroll
  for (int rr = 0; rr < 8; rr++){
    size_t row = (size_t)(r0 + half*8 + rr);
    ao[row*256 + j0] = acc0[rr] + bb0 + query[row*256 + j0];
    ao[row*256 + j1] = acc1[rr] + bb1 + query[row*256 + j1];
  }
}

// ------------------------------- LN kernels (both write f32)
__global__ __launch_bounds__(256) void k_ln(const float* __restrict__ in,
    const float* __restrict__ g, const float* __restrict__ bb, float* __restrict__ out)
{
  __shared__ float w1[4], w2[4];
  const int t = threadIdx.x, r = blockIdx.x;
  float v = in[(size_t)r*256 + t];
  float s1 = v, s2 = v*v;
  #pragma unroll
  for (int o = 32; o > 0; o >>= 1){ s1 += __shfl_down(s1, o); s2 += __shfl_down(s2, o); }
  if ((t & 63) == 0){ w1[t >> 6] = s1; w2[t >> 6] = s2; }
  __syncthreads();
  if (t == 0){
    float a = w1[0] + w1[1] + w1[2] + w1[3];
    float bs = w2[0] + w2[1] + w2[2] + w2[3];
    float mean = a * (1.0f/256.0f);
    float var = bs * (1.0f/256.0f) - mean*mean;
    w1[0] = mean; w2[0] = rsqrtf(var + 1e-5f);
  }
  __syncthreads();
  float mean = w1[0], inv = w2[0];
  out[(size_t)r*256 + t] = (v - mean) * inv * g[t] + bb[t];
}

// ------------------------------- K6: h1 = gelu(x @ W1 + b1), OUT=1024
DEV float gelu_tanh(float x){
  float z = 0.7978845608028654f * (x + 0.044715f * x * x * x);
  float th = 2.0f / (1.0f + __expf(-2.0f * z)) - 1.0f;
  return 0.5f * x * (1.0f + th);
}

__global__ __launch_bounds__(256) void k_ffn1(const float* __restrict__ x,
    const float* __restrict__ W1, const float* __restrict__ b1, bf16* __restrict__ h1)
{
  __shared__ float ins[16][256];
  const int t = threadIdx.x;
  const int r0 = blockIdx.x * 16;
  {
    int row = t >> 4, c0 = (t & 15) * 16;
    const float4* src = (const float4*)(x + (size_t)(r0 + row)*256 + c0);
    float4* d = (float4*)&ins[row][c0];
    d[0] = src[0]; d[1] = src[1]; d[2] = src[2]; d[3] = src[3];
  }
  __syncthreads();
  const int half = t >> 7, jj = t & 127;
  const int j0 = blockIdx.y * 256 + jj, j1 = j0 + 128;
  float acc0[8] = {0,0,0,0,0,0,0,0}, acc1[8] = {0,0,0,0,0,0,0,0};
  for (int i = 0; i < 256; i += 4){
    float w0[4], w1[4];
    #pragma unroll
    for (int u = 0; u < 4; u++){
      w0[u] = W1[(size_t)(i+u)*1024 + j0];
      w1[u] = W1[(size_t)(i+u)*1024 + j1];
    }
    #pragma unroll
    for (int rr = 0; rr < 8; rr++){
      float4 v = *(const float4*)&ins[half*8 + rr][i];
      acc0[rr] += v.x*w0[0] + v.y*w0[1] + v.z*w0[2] + v.w*w0[3];
      acc1[rr] += v.x*w1[0] + v.y*w1[1] + v.z*w1[2] + v.w*w1[3];
    }
  }
  float bb0 = b1[j0], bb1 = b1[j1];
  #pragma unroll
  for (int rr = 0; rr < 8; rr++){
    size_t row = (size_t)(r0 + half*8 + rr);
    h1[row*1024 + j0] = __float2bfloat16(gelu_tanh(acc0[rr] + bb0));
    h1[row*1024 + j1] = __float2bfloat16(gelu_tanh(acc1[rr] + bb1));
  }
}

// ------------------------------- K7: y = x + h1 @ W2 + b2  (IN=1024, chunked)
__global__ __launch_bounds__(256) void k_ffn2(const bf16* __restrict__ h1,
    const float* __restrict__ W2, const float* __restrict__ b2,
    const float* __restrict__ x, float* __restrict__ y)
{
  __shared__ float ins[16][256];
  const int t = threadIdx.x;
  const int r0 = blockIdx.x * 16;
  const int half = t >> 7, jj = t & 127;
  const int j0 = jj, j1 = jj + 128;
  float acc0[8] = {0,0,0,0,0,0,0,0}, acc1[8] = {0,0,0,0,0,0,0,0};
  for (int ib = 0; ib < 4; ib++){
    __syncthreads();
    {
      int row = t >> 4, c0 = (t & 15) * 16;
      const uint4* src = (const uint4*)(h1 + (size_t)(r0 + row)*1024 + ib*256 + c0);
      uint4 a = src[0], b = src[1];
      float* d = &ins[row][c0];
      d[0]=blo(a.x); d[1]=bhi(a.x); d[2]=blo(a.y); d[3]=bhi(a.y);
      d[4]=blo(a.z); d[5]=bhi(a.z); d[6]=blo(a.w); d[7]=bhi(a.w);
      d[8]=blo(b.x); d[9]=bhi(b.x); d[10]=blo(b.y); d[11]=bhi(b.y);
      d[12]=blo(b.z); d[13]=bhi(b.z); d[14]=blo(b.w); d[15]=bhi(b.w);
    }
    __syncthreads();
    for (int i = 0; i < 256; i += 4){
      float w0[4], w1[4];
      #pragma unroll
      for (int u = 0; u < 4; u++){
        w0[u] = W2[(size_t)(ib*256 + i + u)*256 + j0];
        w1[u] = W2[(size_t)(ib*256 + i + u)*256 + j1];
      }
      #pragma unroll
      for (int rr = 0; rr < 8; rr++){
        float4 v = *(const float4*)&ins[half*8 + rr][i];
        acc0[rr] += v.x*w0[0] + v.y*w0[1] + v.z*w0[2] + v.w*w0[3];
        acc1[rr] += v.x*w1[0] + v.y*w1[1] + v.z*w1[2] + v.w*w1[3];
      }
    }
  }
  float bb0 = b2[j0], bb1 = b2[j1];
  #pragma unroll
  for (int rr = 0; rr < 8; rr++){
    size_t row = (size_t)(r0 + half*8 + rr);
    y[row*256 + j0] = acc0[rr] + bb0 + x[row*256 + j0];
    y[row*256 + j1] = acc1[rr] + bb1 + x[row*256 + j1];
  }
}

// ---------------------------------------------------------------- launch
extern "C" void kernel_launch(void* const* d_in, const int* in_sizes, int n_in,
                              void* d_out, int out_size, void* d_ws, size_t ws_size,
                              hipStream_t stream)
{
  const float* query      = (const float*)d_in[0];
  const float* local_feat = (const float*)d_in[1];
  const float* local_spat = (const float*)d_in[2];
  const float* rel_table  = (const float*)d_in[3];
  const float* Wq  = (const float*)d_in[4];   const float* bq  = (const float*)d_in[5];
  const float* Wk  = (const float*)d_in[6];   const float* bk  = (const float*)d_in[7];
  const float* Wv  = (const float*)d_in[8];   const float* bv  = (const float*)d_in[9];
  const float* Wo  = (const float*)d_in[10];  const float* bo  = (const float*)d_in[11];
  const float* g1  = (const float*)d_in[12];  const float* be1 = (const float*)d_in[13];
  const float* W1  = (const float*)d_in[14];  const float* b1  = (const float*)d_in[15];
  const float* W2  = (const float*)d_in[16];  const float* b2  = (const float*)d_in[17];
  const float* g2  = (const float*)d_in[18];  const float* be2 = (const float*)d_in[19];

  char* ws = (char*)d_ws;
  // layout (bytes): qk 16.78M | sbias 128K | q 4.19M | fctx 16.78M | ao 4.19M | x 4.19M | h1 8.39M
  bf16*  qk   = (bf16*) (ws + 0);
  float* sb   = (float*)(ws + 16777216);
  float* q    = (float*)(ws + 16908288);
  bf16*  fctx = (bf16*) (ws + 21102592);
  float* ao   = (float*)(ws + 37879808);
  float* x    = (float*)(ws + 42074112);
  bf16*  h1   = (bf16*) (ws + 46268416);
  float* ctx  = (float*)(ws + 16908288);   // reuse q (dead after k_qk)
  float* y    = (float*)(ws + 37879808);   // reuse ao (dead after k_ln)
  float* out  = (float*)d_out;

  dim3 blk(256);
  k_qproj  <<<dim3(256),    blk, 0, stream>>>(query, Wq, bq, q);
  k_qk     <<<dim3(256, 8), blk, 0, stream>>>(q, Wk, bk, qk, sb);
  k_attn   <<<dim3(4096),   blk, 0, stream>>>(local_feat, local_spat, rel_table, qk, sb, fctx);
  k_ctx    <<<dim3(256),    blk, 0, stream>>>(fctx, Wv, bv, ctx);
  k_attnout<<<dim3(256),    blk, 0, stream>>>(ctx, Wo, bo, query, ao);
  k_ln     <<<dim3(4096),   blk, 0, stream>>>(ao, g1, be1, x);
  k_ffn1   <<<dim3(256, 4), blk, 0, stream>>>(x, W1, b1, h1);
  k_ffn2   <<<dim3(256),    blk, 0, stream>>>(h1, W2, b2, x, y);
  k_ln     <<<dim3(4096),   blk, 0, stream>>>(y, g2, be2, out);
}

// Round 4
// 533.457 us; speedup vs baseline: 1.6453x; 1.6453x over previous
//
#include <hip/hip_runtime.h>
#include <hip/hip_bf16.h>

typedef __hip_bfloat16 bf16;
typedef __attribute__((ext_vector_type(8))) short short8;
typedef __attribute__((ext_vector_type(4))) float float4_;

#define DEV static __device__ __forceinline__

DEV float blo(unsigned w){ return __uint_as_float(w << 16); }
DEV float bhi(unsigned w){ return __uint_as_float(w & 0xffff0000u); }
DEV unsigned short f2bu(float x){ bf16 h = __float2bfloat16(x); unsigned short u; __builtin_memcpy(&u, &h, 2); return u; }
DEV unsigned pack2(float a, float b){ return (unsigned)f2bu(a) | ((unsigned)f2bu(b) << 16); }

DEV float gelu_tanh(float x){
  float z = 0.7978845608028654f * (x + 0.044715f * x * x * x);
  float th = 2.0f / (1.0f + __expf(-2.0f * z)) - 1.0f;
  return 0.5f * x * (1.0f + th);
}

// Dims: B=8, K=512, C=256, HEADS=8, D=32, N=64, FF=1024, HT=9; rows r=b*512+k, M=4096.
// Inputs f32; output f32; intermediates bf16 (weights pre-transposed to N-major bf16).

// ---------------------------------------------------------------- prep: f32 -> bf16 (+transposes)
__global__ __launch_bounds__(256) void k_prep(
    const float* __restrict__ query, const float* __restrict__ Wq,
    const float* __restrict__ Wk, const float* __restrict__ Wv,
    const float* __restrict__ Wo, const float* __restrict__ W1, const float* __restrict__ W2,
    bf16* __restrict__ query_bf, bf16* __restrict__ WqT, bf16* __restrict__ WkP,
    bf16* __restrict__ WvP, bf16* __restrict__ WoT, bf16* __restrict__ W1T, bf16* __restrict__ W2T)
{
  const size_t stride = (size_t)gridDim.x * 256;
  for (size_t i = (size_t)blockIdx.x * 256 + threadIdx.x; i < 1048576; i += stride){
    query_bf[i] = __float2bfloat16(query[i]);
    if (i < 262144){
      { int n = i >> 8,  k = i & 255;  W1T[i] = __float2bfloat16(W1[(size_t)k*1024 + n]); }
      { int n = i >> 10, k = i & 1023; W2T[i] = __float2bfloat16(W2[(size_t)k*256 + n]); }
    }
    if (i < 65536){
      { int n = i >> 8, k = i & 255; WqT[i] = __float2bfloat16(Wq[(size_t)k*256 + n]);
                                     WoT[i] = __float2bfloat16(Wo[(size_t)k*256 + n]); }
      { int h = i >> 13, c = (i >> 5) & 255, d = i & 31;
        WkP[i] = __float2bfloat16(Wk[(size_t)c*256 + h*32 + d]); }
      { int h = i >> 13, d = (i >> 8) & 31, c = i & 255;
        WvP[i] = __float2bfloat16(Wv[(size_t)c*256 + h*32 + d]); }
    }
  }
}

// ---------------------------------------------------------------- MFMA GEMM: C[m][n] = A[m][k] . BT[n][k]
// A bf16 row-major (lda), BT bf16 [N][KDIM]. Tile 64 x NT, 4 waves (wave w: rows 16w..16w+15).
// grid: (M/64, Nslice/NT, heads). EPI: 0=bf16 bias, 1=f32 bias+resid, 2=bf16 bias+gelu.
template<int KDIM, int NT, int EPI>
__global__ __launch_bounds__(256) void k_gemm(
    const bf16* __restrict__ A, int lda, int acolH,
    const bf16* __restrict__ BT, int btH,
    const float* __restrict__ bias,
    const float* __restrict__ resid, int ldr,
    float* __restrict__ Cf, bf16* __restrict__ Cb, int ldc, int ncolH)
{
  constexpr int KB = (KDIM >= 64) ? 64 : 32;
  constexpr int LP = KB + 8;
  constexpr int ASEG = KB / 8;
  __shared__ short As[64][LP];
  __shared__ short Bs[NT][LP];

  const int t = threadIdx.x;
  const int w = t >> 6, l = t & 63, lm = l & 15, lq = l >> 4;
  const int m0 = blockIdx.x * 64;
  const int h = blockIdx.z;
  const size_t acol = (size_t)h * acolH;
  const bf16* Bt = BT + (size_t)h * btH + (size_t)(blockIdx.y * NT) * KDIM;
  const int ncol = h * ncolH + blockIdx.y * NT;

  float4_ acc[NT/16];
  #pragma unroll
  for (int i = 0; i < NT/16; i++) acc[i] = (float4_){0.f,0.f,0.f,0.f};

  for (int k0 = 0; k0 < KDIM; k0 += KB){
    if (k0) __syncthreads();
    for (int i = t; i < 64*ASEG; i += 256){
      int row = i / ASEG, seg = i % ASEG;
      uint4 v = *(const uint4*)(A + (size_t)(m0+row)*lda + acol + k0 + seg*8);
      *(uint4*)&As[row][seg*8] = v;
    }
    for (int i = t; i < NT*ASEG; i += 256){
      int row = i / ASEG, seg = i % ASEG;
      uint4 v = *(const uint4*)(Bt + (size_t)row*KDIM + k0 + seg*8);
      *(uint4*)&Bs[row][seg*8] = v;
    }
    __syncthreads();
    #pragma unroll
    for (int kk = 0; kk < KB/32; kk++){
      short8 af = *(const short8*)&As[w*16 + lm][kk*32 + lq*8];
      #pragma unroll
      for (int nt = 0; nt < NT/16; nt++){
        short8 bfr = *(const short8*)&Bs[nt*16 + lm][kk*32 + lq*8];
        acc[nt] = __builtin_amdgcn_mfma_f32_16x16x32_bf16(af, bfr, acc[nt], 0, 0, 0);
      }
    }
  }

  #pragma unroll
  for (int nt = 0; nt < NT/16; nt++){
    int gcol = ncol + nt*16 + lm;
    float bb = bias ? bias[gcol] : 0.0f;
    #pragma unroll
    for (int rg = 0; rg < 4; rg++){
      int row = m0 + w*16 + lq*4 + rg;
      float v = acc[nt][rg] + bb;
      if (EPI == 0)      Cb[(size_t)row*ldc + gcol] = __float2bfloat16(v);
      else if (EPI == 1) Cf[(size_t)row*ldc + gcol] = v + resid[(size_t)row*ldr + gcol];
      else               Cb[(size_t)row*ldc + gcol] = __float2bfloat16(gelu_tanh(v));
    }
  }
}

// ---------------------------------------------------------------- attention core per (b,k)
// LDS: fs 33792 + qks 8192 + sc 2048 + attn_t 2048 + tab 2592 + bw4 1024 + bix 1024 = ~50.7 KB
__global__ __launch_bounds__(256) void k_attn(
    const float* __restrict__ local_feat, const float* __restrict__ local_spat,
    const float* __restrict__ rel_table, const bf16* __restrict__ qk,
    bf16* __restrict__ fctx)
{
  __shared__ ushort fs[256][66];
  __shared__ float qks[8][256];
  __shared__ float sc[8][64];
  __shared__ float attn_t[64][8];
  __shared__ float tab[648];
  __shared__ float bw4[64][4];
  __shared__ int   bix[64][4];

  const int t = threadIdx.x;
  const int r = blockIdx.x;
  const int b = r >> 9, k = r & 511;

  {
    int cb = t >> 2;
    int nq = (t & 3) * 16;
    #pragma unroll
    for (int p = 0; p < 4; p++){
      int c = p * 64 + cb;
      const float4* src = (const float4*)(local_feat + ((size_t)((b*256 + c)*512 + k))*64 + nq);
      unsigned* d = (unsigned*)&fs[c][nq];
      #pragma unroll
      for (int g = 0; g < 4; g++){
        float4 v = src[g];
        d[g*2+0] = pack2(v.x, v.y);
        d[g*2+1] = pack2(v.z, v.w);
      }
    }
  }
  {
    const uint4* src = (const uint4*)(qk + (size_t)r * 2048 + t * 8);
    uint4 a = *src;
    int h = t >> 5, c0 = (t & 31) * 8;
    float* d = &qks[h][c0];
    d[0]=blo(a.x); d[1]=bhi(a.x); d[2]=blo(a.y); d[3]=bhi(a.y);
    d[4]=blo(a.z); d[5]=bhi(a.z); d[6]=blo(a.w); d[7]=bhi(a.w);
  }
  for (int i = t; i < 648; i += 256) tab[i] = rel_table[i];
  if (t < 64){
    int n = t;
    float2 sxy = *(const float2*)&local_spat[((size_t)r*64 + n)*2];
    float gx = (sxy.x + 1.0f) * 4.0f, gy = (sxy.y + 1.0f) * 4.0f;
    float x0f = floorf(gx), y0f = floorf(gy);
    int xi0 = (int)x0f, yi0 = (int)y0f;
    float wx1 = gx - x0f, wx0 = 1.0f - wx1;
    float wy1 = gy - y0f, wy0 = 1.0f - wy1;
    int xs[4] = {xi0, xi0 + 1, xi0, xi0 + 1};
    int ys[4] = {yi0, yi0, yi0 + 1, yi0 + 1};
    float ww[4] = {wy0*wx0, wy0*wx1, wy1*wx0, wy1*wx1};
    #pragma unroll
    for (int j2 = 0; j2 < 4; j2++){
      int xx = xs[j2], yy = ys[j2];
      bool valid = (xx >= 0) && (xx <= 8) && (yy >= 0) && (yy <= 8);
      int xc = min(max(xx, 0), 8), yc = min(max(yy, 0), 8);
      bix[n][j2] = yc * 9 + xc;
      bw4[n][j2] = valid ? ww[j2] : 0.0f;
    }
  }
  __syncthreads();

  {
    int h = t >> 5, n0 = (t & 31) * 2;
    float s0 = 0.f, s1 = 0.f;
    for (int c = 0; c < 256; c += 4){
      float4 qv = *(const float4*)&qks[h][c];
      unsigned w0 = *(const unsigned*)&fs[c+0][n0];
      unsigned w1 = *(const unsigned*)&fs[c+1][n0];
      unsigned w2 = *(const unsigned*)&fs[c+2][n0];
      unsigned w3 = *(const unsigned*)&fs[c+3][n0];
      s0 += qv.x*blo(w0) + qv.y*blo(w1) + qv.z*blo(w2) + qv.w*blo(w3);
      s1 += qv.x*bhi(w0) + qv.y*bhi(w1) + qv.z*bhi(w2) + qv.w*bhi(w3);
    }
    const float scale = 0.17677669529663687f;
    float bias0 = tab[h*81 + bix[n0][0]] * bw4[n0][0] + tab[h*81 + bix[n0][1]] * bw4[n0][1]
                + tab[h*81 + bix[n0][2]] * bw4[n0][2] + tab[h*81 + bix[n0][3]] * bw4[n0][3];
    int n1 = n0 + 1;
    float bias1 = tab[h*81 + bix[n1][0]] * bw4[n1][0] + tab[h*81 + bix[n1][1]] * bw4[n1][1]
                + tab[h*81 + bix[n1][2]] * bw4[n1][2] + tab[h*81 + bix[n1][3]] * bw4[n1][3];
    sc[h][n0] = s0 * scale + bias0;
    sc[h][n1] = s1 * scale + bias1;
  }
  __syncthreads();

  if (t < 8){
    int h = t;
    float m = -1e30f;
    for (int n = 0; n < 64; n++) m = fmaxf(m, sc[h][n]);
    float s = 0.f;
    for (int n = 0; n < 64; n++){ float e = __expf(sc[h][n] - m); sc[h][n] = e; s += e; }
    float inv = 1.0f / s;
    for (int n = 0; n < 64; n++) attn_t[n][h] = sc[h][n] * inv;
  }
  __syncthreads();

  {
    const int c = t;
    float f[8] = {0,0,0,0,0,0,0,0};
    for (int n = 0; n < 64; n += 2){
      unsigned wa = *(const unsigned*)&fs[c][n];
      float a0 = blo(wa), a1 = bhi(wa);
      float4 A0 = *(const float4*)&attn_t[n][0];
      float4 A1 = *(const float4*)&attn_t[n][4];
      float4 B0 = *(const float4*)&attn_t[n+1][0];
      float4 B1 = *(const float4*)&attn_t[n+1][4];
      f[0] += A0.x*a0 + B0.x*a1;  f[1] += A0.y*a0 + B0.y*a1;
      f[2] += A0.z*a0 + B0.z*a1;  f[3] += A0.w*a0 + B0.w*a1;
      f[4] += A1.x*a0 + B1.x*a1;  f[5] += A1.y*a0 + B1.y*a1;
      f[6] += A1.z*a0 + B1.z*a1;  f[7] += A1.w*a0 + B1.w*a1;
    }
    #pragma unroll
    for (int h = 0; h < 8; h++)
      fctx[(size_t)r*2048 + h*256 + c] = __float2bfloat16(f[h]);
  }
}

// ---------------------------------------------------------------- LayerNorm (f32 out, optional bf16 copy)
__global__ __launch_bounds__(256) void k_ln(const float* __restrict__ in,
    const float* __restrict__ g, const float* __restrict__ bb,
    float* __restrict__ out, bf16* __restrict__ out_bf)
{
  __shared__ float w1[4], w2[4];
  const int t = threadIdx.x, r = blockIdx.x;
  float v = in[(size_t)r*256 + t];
  float s1 = v, s2 = v*v;
  #pragma unroll
  for (int o = 32; o > 0; o >>= 1){ s1 += __shfl_down(s1, o); s2 += __shfl_down(s2, o); }
  if ((t & 63) == 0){ w1[t >> 6] = s1; w2[t >> 6] = s2; }
  __syncthreads();
  if (t == 0){
    float a = w1[0] + w1[1] + w1[2] + w1[3];
    float bs = w2[0] + w2[1] + w2[2] + w2[3];
    float mean = a * (1.0f/256.0f);
    float var = bs * (1.0f/256.0f) - mean*mean;
    w1[0] = mean; w2[0] = rsqrtf(var + 1e-5f);
  }
  __syncthreads();
  float mean = w1[0], inv = w2[0];
  float o = (v - mean) * inv * g[t] + bb[t];
  out[(size_t)r*256 + t] = o;
  if (out_bf) out_bf[(size_t)r*256 + t] = __float2bfloat16(o);
}

// ---------------------------------------------------------------- launch
extern "C" void kernel_launch(void* const* d_in, const int* in_sizes, int n_in,
                              void* d_out, int out_size, void* d_ws, size_t ws_size,
                              hipStream_t stream)
{
  const float* query      = (const float*)d_in[0];
  const float* local_feat = (const float*)d_in[1];
  const float* local_spat = (const float*)d_in[2];
  const float* rel_table  = (const float*)d_in[3];
  const float* Wq  = (const float*)d_in[4];   const float* bq  = (const float*)d_in[5];
  const float* Wk  = (const float*)d_in[6];
  const float* Wv  = (const float*)d_in[8];   const float* bv  = (const float*)d_in[9];
  const float* Wo  = (const float*)d_in[10];  const float* bo  = (const float*)d_in[11];
  const float* g1  = (const float*)d_in[12];  const float* be1 = (const float*)d_in[13];
  const float* W1  = (const float*)d_in[14];  const float* b1  = (const float*)d_in[15];
  const float* W2  = (const float*)d_in[16];  const float* b2  = (const float*)d_in[17];
  const float* g2  = (const float*)d_in[18];  const float* be2 = (const float*)d_in[19];

  char* ws = (char*)d_ws;
  // phase-1 layout (peak 39.3 MB)
  bf16*  qk       = (bf16*)(ws + 0);           // 16 MB [4096][2048]
  bf16*  fctx     = (bf16*)(ws + 16777216);    // 16 MB [4096][2048]
  bf16*  query_bf = (bf16*)(ws + 33554432);    // 2 MB
  bf16*  q_bf     = (bf16*)(ws + 35651584);    // 2 MB
  bf16*  WqT      = (bf16*)(ws + 37748736);    // 128 KB [256][256]
  bf16*  WkP      = (bf16*)(ws + 37879808);    // 128 KB [8][256][32]
  bf16*  WvP      = (bf16*)(ws + 38010880);    // 128 KB [8][32][256]
  bf16*  WoT      = (bf16*)(ws + 38141952);    // 128 KB [256][256]
  bf16*  W1T      = (bf16*)(ws + 38273024);    // 512 KB [1024][256]
  bf16*  W2T      = (bf16*)(ws + 38797312);    // 512 KB [256][1024]
  // phase-2 reuse (qk region dead after k_attn; fctx region dead after ctx gemm)
  bf16*  ctx_bf   = (bf16*)(ws + 0);           // 2 MB
  float* ao       = (float*)(ws + 2097152);    // 4 MB
  float* y        = (float*)(ws + 6291456);    // 4 MB
  bf16*  x_bf     = (bf16*)(ws + 10485760);    // 2 MB
  float* x        = (float*)(ws + 16777216);   // 4 MB
  bf16*  h1       = (bf16*)(ws + 20971520);    // 8 MB
  float* out      = (float*)d_out;

  dim3 blk(256);
  k_prep<<<dim3(1024), blk, 0, stream>>>(query, Wq, Wk, Wv, Wo, W1, W2,
                                         query_bf, WqT, WkP, WvP, WoT, W1T, W2T);
  // q = query @ Wq + bq  -> bf16
  k_gemm<256,64,0><<<dim3(64,4,1), blk, 0, stream>>>(query_bf, 256, 0, WqT, 0, bq,
                                                     nullptr, 0, nullptr, q_bf, 256, 0);
  // qk[r, h*256+c] = q_h . Wk_h[c,:]   (bk dropped: constant over n under softmax)
  k_gemm<32,64,0><<<dim3(64,4,8), blk, 0, stream>>>(q_bf, 256, 32, WkP, 8192, nullptr,
                                                    nullptr, 0, nullptr, qk, 2048, 256);
  k_attn<<<dim3(4096), blk, 0, stream>>>(local_feat, local_spat, rel_table, qk, fctx);
  // ctx[r, h*32+d] = fctx_h . Wv[:,h*32+d] + bv
  k_gemm<256,32,0><<<dim3(64,1,8), blk, 0, stream>>>(fctx, 2048, 256, WvP, 8192, bv,
                                                     nullptr, 0, nullptr, ctx_bf, 256, 32);
  // ao = query + ctx @ Wo + bo  (f32)
  k_gemm<256,64,1><<<dim3(64,4,1), blk, 0, stream>>>(ctx_bf, 256, 0, WoT, 0, bo,
                                                     query, 256, ao, nullptr, 256, 0);
  k_ln<<<dim3(4096), blk, 0, stream>>>(ao, g1, be1, x, x_bf);
  // h1 = gelu(x @ W1 + b1) -> bf16
  k_gemm<256,64,2><<<dim3(64,16,1), blk, 0, stream>>>(x_bf, 256, 0, W1T, 0, b1,
                                                      nullptr, 0, nullptr, h1, 1024, 0);
  // y = x + h1 @ W2 + b2 (f32)
  k_gemm<1024,64,1><<<dim3(64,4,1), blk, 0, stream>>>(h1, 1024, 0, W2T, 0, b2,
                                                      x, 256, y, nullptr, 256, 0);
  k_ln<<<dim3(4096), blk, 0, stream>>>(y, g2, be2, out, nullptr);
}

// Round 5
// 524.923 us; speedup vs baseline: 1.6721x; 1.0163x over previous
//
#include <hip/hip_runtime.h>
#include <hip/hip_bf16.h>

typedef __hip_bfloat16 bf16;
typedef __attribute__((ext_vector_type(8))) short short8;
typedef __attribute__((ext_vector_type(4))) float float4_;

#define DEV static __device__ __forceinline__

DEV float blo(unsigned w){ return __uint_as_float(w << 16); }
DEV float bhi(unsigned w){ return __uint_as_float(w & 0xffff0000u); }
DEV unsigned short f2bu(float x){ bf16 h = __float2bfloat16(x); unsigned short u; __builtin_memcpy(&u, &h, 2); return u; }
DEV unsigned pack2(float a, float b){ return (unsigned)f2bu(a) | ((unsigned)f2bu(b) << 16); }

DEV float gelu_tanh(float x){
  float z = 0.7978845608028654f * (x + 0.044715f * x * x * x);
  float th = 2.0f / (1.0f + __expf(-2.0f * z)) - 1.0f;
  return 0.5f * x * (1.0f + th);
}

// Dims: B=8, K=512, C=256, HEADS=8, D=32, N=64, FF=1024, HT=9; rows r=b*512+k, M=4096.

// ---------------------------------------------------------------- prep: coalesced bf16 convert + LDS-tiled transposes
// blocks 0-15 WqT | 16-31 WoT | 32-95 W1T | 96-159 W2T | 160-191 WvP | 192-199 WkP | 200-263 query_bf
__global__ __launch_bounds__(256) void k_prep(
    const float* __restrict__ query, const float* __restrict__ Wq,
    const float* __restrict__ Wk, const float* __restrict__ Wv,
    const float* __restrict__ Wo, const float* __restrict__ W1, const float* __restrict__ W2,
    bf16* __restrict__ query_bf, bf16* __restrict__ WqT, bf16* __restrict__ WkP,
    bf16* __restrict__ WvP, bf16* __restrict__ WoT, bf16* __restrict__ W1T, bf16* __restrict__ W2T)
{
  __shared__ ushort ts[64][72];
  const int t = threadIdx.x;
  const int bx = blockIdx.x;

  if (bx < 160){
    // 64x64 tile transpose: out[n0+rr][k0+cc] = in[k0+r][n0+c]
    const float* src; bf16* dst; int ldi, ldo, kt, nt;
    if (bx < 16)      { src = Wq; dst = WqT; ldi = 256;  ldo = 256;  kt = bx & 3;        nt = bx >> 2; }
    else if (bx < 32) { src = Wo; dst = WoT; ldi = 256;  ldo = 256;  kt = (bx-16) & 3;   nt = (bx-16) >> 2; }
    else if (bx < 96) { src = W1; dst = W1T; ldi = 1024; ldo = 256;  kt = (bx-32) & 3;   nt = (bx-32) >> 2; }
    else              { src = W2; dst = W2T; ldi = 256;  ldo = 1024; kt = (bx-96) & 15;  nt = (bx-96) >> 4; }
    int k0 = kt * 64, n0 = nt * 64;
    {
      int r = t >> 2, c0 = (t & 3) * 16;
      #pragma unroll
      for (int g = 0; g < 4; g++){
        float4 v = *(const float4*)&src[(size_t)(k0 + r)*ldi + n0 + c0 + g*4];
        ts[r][c0+g*4+0] = f2bu(v.x); ts[r][c0+g*4+1] = f2bu(v.y);
        ts[r][c0+g*4+2] = f2bu(v.z); ts[r][c0+g*4+3] = f2bu(v.w);
      }
    }
    __syncthreads();
    {
      int rr = t >> 2, cc0 = (t & 3) * 16;
      unsigned wbuf[8];
      #pragma unroll
      for (int j = 0; j < 8; j++)
        wbuf[j] = (unsigned)ts[cc0+2*j][rr] | ((unsigned)ts[cc0+2*j+1][rr] << 16);
      uint4* d = (uint4*)(dst + (size_t)(n0 + rr)*ldo + k0 + cc0);
      d[0] = make_uint4(wbuf[0], wbuf[1], wbuf[2], wbuf[3]);
      d[1] = make_uint4(wbuf[4], wbuf[5], wbuf[6], wbuf[7]);
    }
  } else if (bx < 192){
    // WvP[h][d][c] = Wv[c][h*32+d]; tile: 64 c-rows x 32 d
    int idx = bx - 160, h = idx >> 2, kt = idx & 3, k0 = kt * 64;
    {
      int r = t >> 2, d0 = (t & 3) * 8;
      #pragma unroll
      for (int g = 0; g < 2; g++){
        float4 v = *(const float4*)&Wv[(size_t)(k0 + r)*256 + h*32 + d0 + g*4];
        ts[r][d0+g*4+0] = f2bu(v.x); ts[r][d0+g*4+1] = f2bu(v.y);
        ts[r][d0+g*4+2] = f2bu(v.z); ts[r][d0+g*4+3] = f2bu(v.w);
      }
    }
    __syncthreads();
    {
      int d = t >> 3, cc0 = (t & 7) * 8;
      unsigned wbuf[4];
      #pragma unroll
      for (int j = 0; j < 4; j++)
        wbuf[j] = (unsigned)ts[cc0+2*j][d] | ((unsigned)ts[cc0+2*j+1][d] << 16);
      *(uint4*)(WvP + (size_t)h*8192 + (size_t)d*256 + k0 + cc0) =
          make_uint4(wbuf[0], wbuf[1], wbuf[2], wbuf[3]);
    }
  } else if (bx < 200){
    // WkP[h][c][d] = Wk[c][h*32+d] (coalesced slice copy)
    int off = (bx - 192) * 8192;
    #pragma unroll
    for (int g = 0; g < 8; g++){
      int i = off + g*1024 + t*4;
      int h = i >> 13, c = (i >> 5) & 255, d = i & 31;
      float4 v = *(const float4*)&Wk[(size_t)c*256 + h*32 + d];
      *(uint2*)(WkP + i) = make_uint2(pack2(v.x, v.y), pack2(v.z, v.w));
    }
  } else {
    int off = (bx - 200) * 16384;
    #pragma unroll
    for (int g = 0; g < 16; g++){
      int i = off + g*1024 + t*4;
      float4 v = *(const float4*)&query[i];
      *(uint2*)(query_bf + i) = make_uint2(pack2(v.x, v.y), pack2(v.z, v.w));
    }
  }
}

// ---------------------------------------------------------------- MFMA GEMM: C[m][n] = A[m][k] . BT[n][k]
// Tile 64 x NT, 4 waves. EPI: 0=bf16 bias, 2=bf16 bias+gelu.
template<int KDIM, int NT, int EPI>
__global__ __launch_bounds__(256) void k_gemm(
    const bf16* __restrict__ A, int lda, int acolH,
    const bf16* __restrict__ BT, int btH,
    const float* __restrict__ bias,
    bf16* __restrict__ Cb, int ldc, int ncolH)
{
  constexpr int KB = (KDIM >= 64) ? 64 : 32;
  constexpr int LP = KB + 8;
  constexpr int ASEG = KB / 8;
  __shared__ short As[64][LP];
  __shared__ short Bs[NT][LP];

  const int t = threadIdx.x;
  const int w = t >> 6, l = t & 63, lm = l & 15, lq = l >> 4;
  const int m0 = blockIdx.x * 64;
  const int h = blockIdx.z;
  const size_t acol = (size_t)h * acolH;
  const bf16* Bt = BT + (size_t)h * btH + (size_t)(blockIdx.y * NT) * KDIM;
  const int ncol = h * ncolH + blockIdx.y * NT;

  float4_ acc[NT/16];
  #pragma unroll
  for (int i = 0; i < NT/16; i++) acc[i] = (float4_){0.f,0.f,0.f,0.f};

  for (int k0 = 0; k0 < KDIM; k0 += KB){
    if (k0) __syncthreads();
    for (int i = t; i < 64*ASEG; i += 256){
      int row = i / ASEG, seg = i % ASEG;
      uint4 v = *(const uint4*)(A + (size_t)(m0+row)*lda + acol + k0 + seg*8);
      *(uint4*)&As[row][seg*8] = v;
    }
    for (int i = t; i < NT*ASEG; i += 256){
      int row = i / ASEG, seg = i % ASEG;
      uint4 v = *(const uint4*)(Bt + (size_t)row*KDIM + k0 + seg*8);
      *(uint4*)&Bs[row][seg*8] = v;
    }
    __syncthreads();
    #pragma unroll
    for (int kk = 0; kk < KB/32; kk++){
      short8 af = *(const short8*)&As[w*16 + lm][kk*32 + lq*8];
      #pragma unroll
      for (int nt = 0; nt < NT/16; nt++){
        short8 bfr = *(const short8*)&Bs[nt*16 + lm][kk*32 + lq*8];
        acc[nt] = __builtin_amdgcn_mfma_f32_16x16x32_bf16(af, bfr, acc[nt], 0, 0, 0);
      }
    }
  }

  #pragma unroll
  for (int nt = 0; nt < NT/16; nt++){
    int gcol = ncol + nt*16 + lm;
    float bb = bias ? bias[gcol] : 0.0f;
    #pragma unroll
    for (int rg = 0; rg < 4; rg++){
      int row = m0 + w*16 + lq*4 + rg;
      float v = acc[nt][rg] + bb;
      if (EPI == 0) Cb[(size_t)row*ldc + gcol] = __float2bfloat16(v);
      else          Cb[(size_t)row*ldc + gcol] = __float2bfloat16(gelu_tanh(v));
    }
  }
}

// ---------------------------------------------------------------- fused MFMA GEMM (16x256 tile) + bias + resid + LayerNorm
template<int KDIM, int WRITE_BF>
__global__ __launch_bounds__(256) void k_gemm_ln(
    const bf16* __restrict__ A, int lda,
    const bf16* __restrict__ BT,          // [256][KDIM]
    const float* __restrict__ bias,
    const float* __restrict__ resid,      // [M][256]
    const float* __restrict__ gamma, const float* __restrict__ beta,
    float* __restrict__ Cf, bf16* __restrict__ Cb)
{
  constexpr int KB = 64, LP = 72;
  __shared__ short As[16][LP];
  __shared__ short Bs[256][LP];
  __shared__ float2 part[4][16];

  const int t = threadIdx.x;
  const int w = t >> 6, l = t & 63, lm = l & 15, lq = l >> 4;
  const int m0 = blockIdx.x * 16;

  float4_ acc[4];
  #pragma unroll
  for (int i = 0; i < 4; i++) acc[i] = (float4_){0.f,0.f,0.f,0.f};

  for (int k0 = 0; k0 < KDIM; k0 += KB){
    if (k0) __syncthreads();
    if (t < 128){
      int row = t >> 3, seg = t & 7;
      uint4 v = *(const uint4*)(A + (size_t)(m0+row)*lda + k0 + seg*8);
      *(uint4*)&As[row][seg*8] = v;
    }
    for (int i = t; i < 2048; i += 256){
      int row = i >> 3, seg = i & 7;
      uint4 v = *(const uint4*)(BT + (size_t)row*KDIM + k0 + seg*8);
      *(uint4*)&Bs[row][seg*8] = v;
    }
    __syncthreads();
    #pragma unroll
    for (int kk = 0; kk < 2; kk++){
      short8 af = *(const short8*)&As[lm][kk*32 + lq*8];
      #pragma unroll
      for (int nt = 0; nt < 4; nt++){
        short8 bfr = *(const short8*)&Bs[w*64 + nt*16 + lm][kk*32 + lq*8];
        acc[nt] = __builtin_amdgcn_mfma_f32_16x16x32_bf16(af, bfr, acc[nt], 0, 0, 0);
      }
    }
  }

  // epilogue: v = acc + bias + resid; LN over the 256 cols of each row
  float v[4][4];
  float s1[4] = {0,0,0,0}, s2[4] = {0,0,0,0};
  #pragma unroll
  for (int nt = 0; nt < 4; nt++){
    int col = w*64 + nt*16 + lm;
    float bb = bias[col];
    #pragma unroll
    for (int rg = 0; rg < 4; rg++){
      int row = m0 + lq*4 + rg;
      float x = acc[nt][rg] + bb + resid[(size_t)row*256 + col];
      v[nt][rg] = x;
      s1[rg] += x; s2[rg] += x*x;
    }
  }
  #pragma unroll
  for (int off = 1; off < 16; off <<= 1){
    #pragma unroll
    for (int rg = 0; rg < 4; rg++){
      s1[rg] += __shfl_xor(s1[rg], off);
      s2[rg] += __shfl_xor(s2[rg], off);
    }
  }
  if (lm == 0){
    #pragma unroll
    for (int rg = 0; rg < 4; rg++)
      part[w][lq*4 + rg] = make_float2(s1[rg], s2[rg]);
  }
  __syncthreads();
  #pragma unroll
  for (int rg = 0; rg < 4; rg++){
    int rl = lq*4 + rg;
    float S1 = part[0][rl].x + part[1][rl].x + part[2][rl].x + part[3][rl].x;
    float S2 = part[0][rl].y + part[1][rl].y + part[2][rl].y + part[3][rl].y;
    float mean = S1 * (1.0f/256.0f);
    float var  = S2 * (1.0f/256.0f) - mean*mean;
    float inv  = rsqrtf(var + 1e-5f);
    #pragma unroll
    for (int nt = 0; nt < 4; nt++){
      int col = w*64 + nt*16 + lm;
      float o = (v[nt][rg] - mean) * inv * gamma[col] + beta[col];
      size_t idx = (size_t)(m0 + rl)*256 + col;
      Cf[idx] = o;
      if (WRITE_BF) Cb[idx] = __float2bfloat16(o);
    }
  }
}

// ---------------------------------------------------------------- attention core per (b,k)
// LDS: fs 33792 + qks 8192 + attn_t 3072 + tab 2592 + bw4 1024 + bix 1024 = 49696 B
__global__ __launch_bounds__(256) void k_attn(
    const float* __restrict__ local_feat, const float* __restrict__ local_spat,
    const float* __restrict__ rel_table, const bf16* __restrict__ qk,
    bf16* __restrict__ fctx)
{
  __shared__ ushort fs[256][66];
  __shared__ float qks[8][256];
  __shared__ float attn_t[64][12];
  __shared__ float tab[648];
  __shared__ float bw4[64][4];
  __shared__ int   bix[64][4];

  const int t = threadIdx.x;
  const int r = blockIdx.x;
  const int b = r >> 9, k = r & 511;

  {
    int cb = t >> 2;
    int nq = (t & 3) * 16;
    #pragma unroll
    for (int p = 0; p < 4; p++){
      int c = p * 64 + cb;
      const float4* src = (const float4*)(local_feat + ((size_t)((b*256 + c)*512 + k))*64 + nq);
      unsigned* d = (unsigned*)&fs[c][nq];
      #pragma unroll
      for (int g = 0; g < 4; g++){
        float4 v = src[g];
        d[g*2+0] = pack2(v.x, v.y);
        d[g*2+1] = pack2(v.z, v.w);
      }
    }
  }
  {
    const uint4* src = (const uint4*)(qk + (size_t)r * 2048 + t * 8);
    uint4 a = *src;
    int h = t >> 5, c0 = (t & 31) * 8;
    float* d = &qks[h][c0];
    d[0]=blo(a.x); d[1]=bhi(a.x); d[2]=blo(a.y); d[3]=bhi(a.y);
    d[4]=blo(a.z); d[5]=bhi(a.z); d[6]=blo(a.w); d[7]=bhi(a.w);
  }
  for (int i = t; i < 648; i += 256) tab[i] = rel_table[i];
  if (t < 64){
    int n = t;
    float2 sxy = *(const float2*)&local_spat[((size_t)r*64 + n)*2];
    float gx = (sxy.x + 1.0f) * 4.0f, gy = (sxy.y + 1.0f) * 4.0f;
    float x0f = floorf(gx), y0f = floorf(gy);
    int xi0 = (int)x0f, yi0 = (int)y0f;
    float wx1 = gx - x0f, wx0 = 1.0f - wx1;
    float wy1 = gy - y0f, wy0 = 1.0f - wy1;
    int xs[4] = {xi0, xi0 + 1, xi0, xi0 + 1};
    int ys[4] = {yi0, yi0, yi0 + 1, yi0 + 1};
    float ww[4] = {wy0*wx0, wy0*wx1, wy1*wx0, wy1*wx1};
    #pragma unroll
    for (int j2 = 0; j2 < 4; j2++){
      int xx = xs[j2], yy = ys[j2];
      bool valid = (xx >= 0) && (xx <= 8) && (yy >= 0) && (yy <= 8);
      int xc = min(max(xx, 0), 8), yc = min(max(yy, 0), 8);
      bix[n][j2] = yc * 9 + xc;
      bw4[n][j2] = valid ? ww[j2] : 0.0f;
    }
  }
  __syncthreads();

  // scores + fused softmax (each 32-lane half-wave owns one head)
  {
    int h = t >> 5, n0 = (t & 31) * 2;
    float s0 = 0.f, s1 = 0.f;
    for (int c = 0; c < 256; c += 4){
      float4 qv = *(const float4*)&qks[h][c];
      unsigned w0 = *(const unsigned*)&fs[c+0][n0];
      unsigned w1 = *(const unsigned*)&fs[c+1][n0];
      unsigned w2 = *(const unsigned*)&fs[c+2][n0];
      unsigned w3 = *(const unsigned*)&fs[c+3][n0];
      s0 += qv.x*blo(w0) + qv.y*blo(w1) + qv.z*blo(w2) + qv.w*blo(w3);
      s1 += qv.x*bhi(w0) + qv.y*bhi(w1) + qv.z*bhi(w2) + qv.w*bhi(w3);
    }
    const float scale = 0.17677669529663687f;
    int n1 = n0 + 1;
    float bias0 = tab[h*81 + bix[n0][0]] * bw4[n0][0] + tab[h*81 + bix[n0][1]] * bw4[n0][1]
                + tab[h*81 + bix[n0][2]] * bw4[n0][2] + tab[h*81 + bix[n0][3]] * bw4[n0][3];
    float bias1 = tab[h*81 + bix[n1][0]] * bw4[n1][0] + tab[h*81 + bix[n1][1]] * bw4[n1][1]
                + tab[h*81 + bix[n1][2]] * bw4[n1][2] + tab[h*81 + bix[n1][3]] * bw4[n1][3];
    float sc0 = s0 * scale + bias0;
    float sc1 = s1 * scale + bias1;
    float m = fmaxf(sc0, sc1);
    #pragma unroll
    for (int off = 1; off < 32; off <<= 1) m = fmaxf(m, __shfl_xor(m, off));
    float e0 = __expf(sc0 - m), e1 = __expf(sc1 - m);
    float s = e0 + e1;
    #pragma unroll
    for (int off = 1; off < 32; off <<= 1) s += __shfl_xor(s, off);
    float inv = 1.0f / s;
    attn_t[n0][h] = e0 * inv;
    attn_t[n1][h] = e1 * inv;
  }
  __syncthreads();

  // fctx[h][c] = sum_n attn[h][n] * feats[c][n]; thread t owns channel c=t
  {
    const int c = t;
    float f[8] = {0,0,0,0,0,0,0,0};
    for (int n = 0; n < 64; n += 2){
      unsigned wa = *(const unsigned*)&fs[c][n];
      float a0 = blo(wa), a1 = bhi(wa);
      float4 A0 = *(const float4*)&attn_t[n][0];
      float4 A1 = *(const float4*)&attn_t[n][4];
      float4 B0 = *(const float4*)&attn_t[n+1][0];
      float4 B1 = *(const float4*)&attn_t[n+1][4];
      f[0] += A0.x*a0 + B0.x*a1;  f[1] += A0.y*a0 + B0.y*a1;
      f[2] += A0.z*a0 + B0.z*a1;  f[3] += A0.w*a0 + B0.w*a1;
      f[4] += A1.x*a0 + B1.x*a1;  f[5] += A1.y*a0 + B1.y*a1;
      f[6] += A1.z*a0 + B1.z*a1;  f[7] += A1.w*a0 + B1.w*a1;
    }
    #pragma unroll
    for (int h = 0; h < 8; h++)
      fctx[(size_t)r*2048 + h*256 + c] = __float2bfloat16(f[h]);
  }
}

// ---------------------------------------------------------------- launch
extern "C" void kernel_launch(void* const* d_in, const int* in_sizes, int n_in,
                              void* d_out, int out_size, void* d_ws, size_t ws_size,
                              hipStream_t stream)
{
  const float* query      = (const float*)d_in[0];
  const float* local_feat = (const float*)d_in[1];
  const float* local_spat = (const float*)d_in[2];
  const float* rel_table  = (const float*)d_in[3];
  const float* Wq  = (const float*)d_in[4];   const float* bq  = (const float*)d_in[5];
  const float* Wk  = (const float*)d_in[6];
  const float* Wv  = (const float*)d_in[8];   const float* bv  = (const float*)d_in[9];
  const float* Wo  = (const float*)d_in[10];  const float* bo  = (const float*)d_in[11];
  const float* g1  = (const float*)d_in[12];  const float* be1 = (const float*)d_in[13];
  const float* W1  = (const float*)d_in[14];  const float* b1  = (const float*)d_in[15];
  const float* W2  = (const float*)d_in[16];  const float* b2  = (const float*)d_in[17];
  const float* g2  = (const float*)d_in[18];  const float* be2 = (const float*)d_in[19];

  char* ws = (char*)d_ws;
  bf16*  qk       = (bf16*)(ws + 0);           // 16 MB [4096][2048]
  bf16*  fctx     = (bf16*)(ws + 16777216);    // 16 MB [4096][2048]
  bf16*  query_bf = (bf16*)(ws + 33554432);    // 2 MB
  bf16*  q_bf     = (bf16*)(ws + 35651584);    // 2 MB
  bf16*  WqT      = (bf16*)(ws + 37748736);    // 128 KB [256][256]
  bf16*  WkP      = (bf16*)(ws + 37879808);    // 128 KB [8][256][32]
  bf16*  WvP      = (bf16*)(ws + 38010880);    // 128 KB [8][32][256]
  bf16*  WoT      = (bf16*)(ws + 38141952);    // 128 KB [256][256]
  bf16*  W1T      = (bf16*)(ws + 38273024);    // 512 KB [1024][256]
  bf16*  W2T      = (bf16*)(ws + 38797312);    // 512 KB [256][1024]
  // phase-2 reuse (qk region dead after k_attn; fctx region dead after ctx gemm)
  bf16*  ctx_bf   = (bf16*)(ws + 0);           // 2 MB
  float* x        = (float*)(ws + 2097152);    // 4 MB
  bf16*  x_bf     = (bf16*)(ws + 6291456);     // 2 MB
  bf16*  h1       = (bf16*)(ws + 20971520);    // 8 MB
  float* out      = (float*)d_out;

  dim3 blk(256);
  k_prep<<<dim3(264), blk, 0, stream>>>(query, Wq, Wk, Wv, Wo, W1, W2,
                                        query_bf, WqT, WkP, WvP, WoT, W1T, W2T);
  // q = query @ Wq + bq
  k_gemm<256,64,0><<<dim3(64,4,1), blk, 0, stream>>>(query_bf, 256, 0, WqT, 0, bq, q_bf, 256, 0);
  // qk[r, h*256+c] = q_h . Wk_h[c,:]
  k_gemm<32,64,0><<<dim3(64,4,8), blk, 0, stream>>>(q_bf, 256, 32, WkP, 8192, nullptr, qk, 2048, 256);
  k_attn<<<dim3(4096), blk, 0, stream>>>(local_feat, local_spat, rel_table, qk, fctx);
  // ctx[r, h*32+d] = fctx_h . Wv[:,h*32+d] + bv
  k_gemm<256,32,0><<<dim3(64,1,8), blk, 0, stream>>>(fctx, 2048, 256, WvP, 8192, bv, ctx_bf, 256, 32);
  // x = LN1(query + ctx @ Wo + bo)  (f32 + bf16)
  k_gemm_ln<256,1><<<dim3(256), blk, 0, stream>>>(ctx_bf, 256, WoT, bo, query, g1, be1, x, x_bf);
  // h1 = gelu(x @ W1 + b1)
  k_gemm<256,64,2><<<dim3(64,16,1), blk, 0, stream>>>(x_bf, 256, 0, W1T, 0, b1, h1, 1024, 0);
  // out = LN2(x + h1 @ W2 + b2)
  k_gemm_ln<1024,0><<<dim3(256), blk, 0, stream>>>(h1, 1024, W2T, b2, x, g2, be2, out, nullptr);
}